// Round 1
// baseline (1519.817 us; speedup 1.0000x reference)
//
#include <hip/hip_runtime.h>
#include <math.h>

// ---------------------------------------------------------------------------
// GAT network: 4 layers, N=50000 nodes, E=1.6M edges, edge_dim=8.
// L0: in64 -> H1,C64 concat, relu
// L1: 64   -> H2,C64 mean,   relu
// L2: 64   -> H2,C64 mean,   relu
// L3: 64   -> H1,C2  concat, no relu
// ---------------------------------------------------------------------------

__device__ __forceinline__ float wave_max64(float v) {
#pragma unroll
  for (int o = 32; o >= 1; o >>= 1) v = fmaxf(v, __shfl_xor(v, o));
  return v;
}
__device__ __forceinline__ float wave_sum64(float v) {
#pragma unroll
  for (int o = 32; o >= 1; o >>= 1) v += __shfl_xor(v, o);
  return v;
}

// --------------------------- CSR build ------------------------------------

__global__ void hist_kernel(const int* __restrict__ dst,
                            const float* __restrict__ ea,
                            int* __restrict__ cnt,
                            float* __restrict__ loop_sum,
                            int E_) {
  int e = blockIdx.x * 256 + threadIdx.x;
  if (e >= E_) return;
  int d = dst[e];
  atomicAdd(&cnt[d], 1);
  const float4* v = reinterpret_cast<const float4*>(ea + (size_t)e * 8);
  float4 a = v[0], b = v[1];
  float* ls = loop_sum + (size_t)d * 8;
  unsafeAtomicAdd(ls + 0, a.x);
  unsafeAtomicAdd(ls + 1, a.y);
  unsafeAtomicAdd(ls + 2, a.z);
  unsafeAtomicAdd(ls + 3, a.w);
  unsafeAtomicAdd(ls + 4, b.x);
  unsafeAtomicAdd(ls + 5, b.y);
  unsafeAtomicAdd(ls + 6, b.z);
  unsafeAtomicAdd(ls + 7, b.w);
}

__global__ void loopattr_kernel(float* __restrict__ loop,
                                const int* __restrict__ cnt, int n8) {
  int i = blockIdx.x * 256 + threadIdx.x;
  if (i >= n8) return;
  float c = fmaxf((float)cnt[i >> 3], 1.f);
  loop[i] = loop[i] / c;
}

__global__ void scan_kernel(const int* __restrict__ cnt,
                            int* __restrict__ row_ptr,
                            int* __restrict__ cursor, int n) {
  __shared__ int sd[1024];
  __shared__ int s_carry;
  const int t = threadIdx.x;
  if (t == 0) s_carry = 0;
  __syncthreads();
  for (int base = 0; base < n; base += 1024) {
    int i = base + t;
    int v = (i < n) ? (cnt[i] + 1) : 0;  // +1 self loop
    sd[t] = v;
    __syncthreads();
#pragma unroll
    for (int o = 1; o < 1024; o <<= 1) {
      int u = (t >= o) ? sd[t - o] : 0;
      __syncthreads();
      sd[t] += u;
      __syncthreads();
    }
    int incl = sd[t];
    int carry = s_carry;
    int excl = carry + incl - v;
    if (i < n) { row_ptr[i] = excl; cursor[i] = excl; }
    __syncthreads();
    if (t == 1023) s_carry = carry + incl;
    __syncthreads();
  }
  if (t == 0) row_ptr[n] = s_carry;
}

__global__ void scatter_kernel(const int* __restrict__ src,
                               const int* __restrict__ dst,
                               int* __restrict__ cursor,
                               int* __restrict__ col_src,
                               int* __restrict__ eid, int E_) {
  int e = blockIdx.x * 256 + threadIdx.x;
  if (e >= E_) return;
  int d = dst[e];
  int p = atomicAdd(&cursor[d], 1);
  col_src[p] = src[e];
  eid[p] = e;
}

__global__ void selfloop_kernel(int* __restrict__ cursor,
                                int* __restrict__ col_src,
                                int* __restrict__ eid, int n, int E_) {
  int i = blockIdx.x * 256 + threadIdx.x;
  if (i >= n) return;
  int p = atomicAdd(&cursor[i], 1);
  col_src[p] = i;
  eid[p] = E_ + i;
}

// --------------------------- per-layer kernels -----------------------------

// comb[h,d] = sum_c We[d, h*C+c] * ae[h,c]
template <int H, int C>
__global__ void comb_kernel(const float* __restrict__ We,
                            const float* __restrict__ ae,
                            float* __restrict__ comb) {
  int t = threadIdx.x;
  if (t >= H * 8) return;
  int h = t >> 3, d = t & 7;
  float s = 0.f;
  for (int c = 0; c < C; ++c) s += We[d * (H * C) + h * C + c] * ae[h * C + c];
  comb[t] = s;
}

// h = x @ W  (x: [n,64], W: [64,HC]); fused al_src/al_dst epilogue.
template <int HC, int H>
__global__ __launch_bounds__(256) void gemm_proj_kernel(
    const float* __restrict__ x, const float* __restrict__ W,
    const float* __restrict__ a_src, const float* __restrict__ a_dst,
    float* __restrict__ h, float* __restrict__ al_src,
    float* __restrict__ al_dst, int n) {
  constexpr int IN = 64;
  constexpr int C = HC / H;
  __shared__ float xs[32][IN];
  const int tid = threadIdx.x;
  const int j = tid % HC;
  const int rsub = tid / HC;
  constexpr int RPP = 256 / HC > 0 ? 256 / HC : 1;

  float wr[IN];
#pragma unroll
  for (int k = 0; k < IN; ++k) wr[k] = W[k * HC + j];
  const float asj = a_src[j];
  const float adj = a_dst[j];

  const int row0 = blockIdx.x * 32;
  {
    const float4* xv = reinterpret_cast<const float4*>(x);
    float4* xsv = reinterpret_cast<float4*>(&xs[0][0]);
    for (int i = tid; i < 32 * IN / 4; i += 256) {
      int r = i / (IN / 4);
      int row = row0 + r;
      float4 v = make_float4(0.f, 0.f, 0.f, 0.f);
      if (row < n) v = xv[(size_t)row * (IN / 4) + (i % (IN / 4))];
      xsv[i] = v;
    }
  }
  __syncthreads();

  for (int rb = 0; rb < 32; rb += RPP) {
    int r = rb + rsub;
    if (r >= 32) break;  // wave-uniform (only for HC=2 tails)
    int row = row0 + r;
    float acc = 0.f;
#pragma unroll
    for (int k4 = 0; k4 < IN / 4; ++k4) {
      float4 xv = *reinterpret_cast<const float4*>(&xs[r][k4 * 4]);
      acc += xv.x * wr[k4 * 4 + 0] + xv.y * wr[k4 * 4 + 1] +
             xv.z * wr[k4 * 4 + 2] + xv.w * wr[k4 * 4 + 3];
    }
    if (row < n) h[(size_t)row * HC + j] = acc;
    // fused al_src / al_dst reductions over the C lanes of each head
    float ps = acc * asj;
    float pd = acc * adj;
#pragma unroll
    for (int o = C / 2; o >= 1; o >>= 1) {
      ps += __shfl_xor(ps, o);
      pd += __shfl_xor(pd, o);
    }
    if (row < n && (j % C) == 0) {
      int hh = j / C;
      al_src[(size_t)row * H + hh] = ps;
      al_dst[(size_t)row * H + hh] = pd;
    }
  }
}

// fused attention softmax + aggregation; one wave per node.
template <int H, int C, bool CONCAT, bool RELU>
__global__ __launch_bounds__(256) void gat_node_kernel(
    const int* __restrict__ row_ptr, const int* __restrict__ col_src,
    const int* __restrict__ eid, const float* __restrict__ edge_attr,
    const float* __restrict__ loop_attr, const float* __restrict__ h_proj,
    const float* __restrict__ al_src, const float* __restrict__ al_dst,
    const float* __restrict__ comb, const float* __restrict__ bias,
    float* __restrict__ out, int n, int E_) {
  const int lane = threadIdx.x & 63;
  const int node = blockIdx.x * 4 + (threadIdx.x >> 6);
  if (node >= n) return;

  float cb[H][8];
#pragma unroll
  for (int h = 0; h < H; ++h)
#pragma unroll
    for (int d = 0; d < 8; ++d) cb[h][d] = comb[h * 8 + d];

  float adn[H];
#pragma unroll
  for (int h = 0; h < H; ++h) adn[h] = al_dst[(size_t)node * H + h];

  const int start = row_ptr[node];
  const int end = row_ptr[node + 1];

  float m[H], den[H], acc[H];
#pragma unroll
  for (int h = 0; h < H; ++h) { m[h] = -INFINITY; den[h] = 0.f; acc[h] = 0.f; }

  for (int base = start; base < end; base += 64) {
    const int i = base + lane;
    const bool valid = (i < end);
    int s = 0;
    float alpha[H];
    if (valid) {
      s = col_src[i];
      int id = eid[i];
      const float* eaP = (id < E_) ? (edge_attr + (size_t)id * 8)
                                   : (loop_attr + (size_t)(id - E_) * 8);
      float4 ea0 = *reinterpret_cast<const float4*>(eaP);
      float4 ea1 = *reinterpret_cast<const float4*>(eaP + 4);
#pragma unroll
      for (int h = 0; h < H; ++h) {
        float a = al_src[(size_t)s * H + h] + adn[h];
        a += ea0.x * cb[h][0] + ea0.y * cb[h][1] + ea0.z * cb[h][2] +
             ea0.w * cb[h][3] + ea1.x * cb[h][4] + ea1.y * cb[h][5] +
             ea1.z * cb[h][6] + ea1.w * cb[h][7];
        alpha[h] = (a > 0.f) ? a : 0.2f * a;  // leaky_relu 0.2
      }
    } else {
#pragma unroll
      for (int h = 0; h < H; ++h) alpha[h] = -INFINITY;
    }

    float ex[H];
#pragma unroll
    for (int h = 0; h < H; ++h) {
      float cm = wave_max64(alpha[h]);
      float nm = fmaxf(m[h], cm);          // finite: every chunk has >=1 edge
      float r = expf(m[h] - nm);           // exp(-inf)=0 on first chunk
      ex[h] = valid ? expf(alpha[h] - nm) : 0.f;
      float cs = wave_sum64(ex[h]);
      den[h] = den[h] * r + cs;
      acc[h] *= r;
      m[h] = nm;
    }

    const int cntc = min(64, end - base);
    for (int t = 0; t < cntc; ++t) {
      int sv = __shfl(s, t);
      const float* hp = h_proj + (size_t)sv * (H * C);
#pragma unroll
      for (int h = 0; h < H; ++h) {
        float w = __shfl(ex[h], t);
        if (C >= 64 || lane < C) acc[h] += w * hp[h * C + lane];
      }
    }
  }

  if (lane < C) {
    if (CONCAT) {
#pragma unroll
      for (int h = 0; h < H; ++h) {
        float v = acc[h] / (den[h] + 1e-16f) + bias[h * C + lane];
        if (RELU) v = fmaxf(v, 0.f);
        out[(size_t)node * (H * C) + h * C + lane] = v;
      }
    } else {
      float v = 0.f;
#pragma unroll
      for (int h = 0; h < H; ++h) v += acc[h] / (den[h] + 1e-16f);
      v = v * (1.f / H) + bias[lane];
      if (RELU) v = fmaxf(v, 0.f);
      out[(size_t)node * C + lane] = v;
    }
  }
}

// --------------------------- launch ----------------------------------------

static inline size_t align_up(size_t v, size_t a) { return (v + a - 1) & ~(a - 1); }

extern "C" void kernel_launch(void* const* d_in, const int* in_sizes, int n_in,
                              void* d_out, int out_size, void* d_ws,
                              size_t ws_size, hipStream_t stream) {
  const float* x = (const float*)d_in[0];
  const int* ei = (const int*)d_in[1];
  const float* ea = (const float*)d_in[2];

  const int N = in_sizes[0] / 64;
  const int E = in_sizes[1] / 2;
  const int* src0 = ei;
  const int* dst0 = ei + E;

  const float* W[4] = {(const float*)d_in[3], (const float*)d_in[9],
                       (const float*)d_in[15], (const float*)d_in[21]};
  const float* As[4] = {(const float*)d_in[4], (const float*)d_in[10],
                        (const float*)d_in[16], (const float*)d_in[22]};
  const float* Ad[4] = {(const float*)d_in[5], (const float*)d_in[11],
                        (const float*)d_in[17], (const float*)d_in[23]};
  const float* We[4] = {(const float*)d_in[6], (const float*)d_in[12],
                        (const float*)d_in[18], (const float*)d_in[24]};
  const float* Ae[4] = {(const float*)d_in[7], (const float*)d_in[13],
                        (const float*)d_in[19], (const float*)d_in[25]};
  const float* B[4] = {(const float*)d_in[8], (const float*)d_in[14],
                       (const float*)d_in[20], (const float*)d_in[26]};

  // workspace carve-up
  char* p = (char*)d_ws;
  size_t off = 0;
  auto carve = [&](size_t bytes) {
    void* r = p + off;
    off = align_up(off + bytes, 256);
    return r;
  };
  int* cnt = (int*)carve((size_t)N * 4);
  int* row_ptr = (int*)carve((size_t)(N + 1) * 4);
  int* cursor = (int*)carve((size_t)N * 4);
  int* col_src = (int*)carve((size_t)(E + N) * 4);
  int* eid = (int*)carve((size_t)(E + N) * 4);
  float* loop_attr = (float*)carve((size_t)N * 8 * 4);
  float* comb = (float*)carve(256);
  float* al_src = (float*)carve((size_t)N * 2 * 4);
  float* al_dst = (float*)carve((size_t)N * 2 * 4);
  float* h_proj = (float*)carve((size_t)N * 128 * 4);
  float* buf_a = (float*)carve((size_t)N * 64 * 4);
  float* buf_b = (float*)carve((size_t)N * 64 * 4);
  (void)ws_size;

  // ---- CSR + self-loop attr (graph is layer-invariant) ----
  hipMemsetAsync(cnt, 0, (size_t)N * 4, stream);
  hipMemsetAsync(loop_attr, 0, (size_t)N * 8 * 4, stream);
  hist_kernel<<<(E + 255) / 256, 256, 0, stream>>>(dst0, ea, cnt, loop_attr, E);
  loopattr_kernel<<<(N * 8 + 255) / 256, 256, 0, stream>>>(loop_attr, cnt, N * 8);
  scan_kernel<<<1, 1024, 0, stream>>>(cnt, row_ptr, cursor, N);
  scatter_kernel<<<(E + 255) / 256, 256, 0, stream>>>(src0, dst0, cursor,
                                                      col_src, eid, E);
  selfloop_kernel<<<(N + 255) / 256, 256, 0, stream>>>(cursor, col_src, eid, N, E);

  const int gemm_grid = (N + 31) / 32;
  const int node_grid = (N + 3) / 4;

  // ---- layer 0: in64 -> H1,C64, concat, relu ----
  gemm_proj_kernel<64, 1><<<gemm_grid, 256, 0, stream>>>(
      x, W[0], As[0], Ad[0], h_proj, al_src, al_dst, N);
  comb_kernel<1, 64><<<1, 64, 0, stream>>>(We[0], Ae[0], comb);
  gat_node_kernel<1, 64, true, true><<<node_grid, 256, 0, stream>>>(
      row_ptr, col_src, eid, ea, loop_attr, h_proj, al_src, al_dst, comb, B[0],
      buf_a, N, E);

  // ---- layer 1: 64 -> H2,C64, mean, relu ----
  gemm_proj_kernel<128, 2><<<gemm_grid, 256, 0, stream>>>(
      buf_a, W[1], As[1], Ad[1], h_proj, al_src, al_dst, N);
  comb_kernel<2, 64><<<1, 64, 0, stream>>>(We[1], Ae[1], comb);
  gat_node_kernel<2, 64, false, true><<<node_grid, 256, 0, stream>>>(
      row_ptr, col_src, eid, ea, loop_attr, h_proj, al_src, al_dst, comb, B[1],
      buf_b, N, E);

  // ---- layer 2: 64 -> H2,C64, mean, relu ----
  gemm_proj_kernel<128, 2><<<gemm_grid, 256, 0, stream>>>(
      buf_b, W[2], As[2], Ad[2], h_proj, al_src, al_dst, N);
  comb_kernel<2, 64><<<1, 64, 0, stream>>>(We[2], Ae[2], comb);
  gat_node_kernel<2, 64, false, true><<<node_grid, 256, 0, stream>>>(
      row_ptr, col_src, eid, ea, loop_attr, h_proj, al_src, al_dst, comb, B[2],
      buf_a, N, E);

  // ---- layer 3: 64 -> H1,C2, concat, no relu ----
  gemm_proj_kernel<2, 1><<<gemm_grid, 256, 0, stream>>>(
      buf_a, W[3], As[3], Ad[3], h_proj, al_src, al_dst, N);
  comb_kernel<1, 2><<<1, 64, 0, stream>>>(We[3], Ae[3], comb);
  gat_node_kernel<1, 2, true, false><<<node_grid, 256, 0, stream>>>(
      row_ptr, col_src, eid, ea, loop_attr, h_proj, al_src, al_dst, comb, B[3],
      (float*)d_out, N, E);
}

// Round 2
// 772.296 us; speedup vs baseline: 1.9679x; 1.9679x over previous
//
#include <hip/hip_runtime.h>
#include <math.h>

// ---------------------------------------------------------------------------
// GAT network: 4 layers, N=50000 nodes, E=1.6M edges, edge_dim=8.
// L0: in64 -> H1,C64 concat, relu
// L1: 64   -> H2,C64 mean,   relu
// L2: 64   -> H2,C64 mean,   relu
// L3: 64   -> H1,C2  concat, no relu
//
// Preprocessing (per call, graph-invariant across layers):
//   cnt -> 3-pass scan -> CSR scatter -> self-loop append ->
//   edge_prep: per-node gather of edge_attr computes loop-attr mean AND the
//   per-edge attention dot (ea . comb_l[h]) for all 4 layers in one pass.
// Layer kernels then never touch edge_attr/eid again.
// ---------------------------------------------------------------------------

__device__ __forceinline__ float wave_max64(float v) {
#pragma unroll
  for (int o = 32; o >= 1; o >>= 1) v = fmaxf(v, __shfl_xor(v, o));
  return v;
}
__device__ __forceinline__ float wave_sum64(float v) {
#pragma unroll
  for (int o = 32; o >= 1; o >>= 1) v += __shfl_xor(v, o);
  return v;
}
__device__ __forceinline__ float dot8(const float4& a, const float4& b,
                                      const float* c) {
  return a.x * c[0] + a.y * c[1] + a.z * c[2] + a.w * c[3] + b.x * c[4] +
         b.y * c[5] + b.z * c[6] + b.w * c[7];
}

// --------------------------- CSR build ------------------------------------

__global__ void hist_kernel(const int* __restrict__ dst, int* __restrict__ cnt,
                            int E_) {
  int e = blockIdx.x * 256 + threadIdx.x;
  if (e >= E_) return;
  atomicAdd(&cnt[dst[e]], 1);
}

// pass 1: per-block (1024 elems) local exclusive scan of (cnt[i]+1)
__global__ __launch_bounds__(256) void scan1_kernel(const int* __restrict__ cnt,
                                                    int* __restrict__ rowp,
                                                    int* __restrict__ bsum,
                                                    int n) {
  __shared__ int sd[256];
  const int t = threadIdx.x;
  const int base = blockIdx.x * 1024 + t * 4;
  int v0 = (base + 0 < n) ? cnt[base + 0] + 1 : 0;
  int v1 = (base + 1 < n) ? cnt[base + 1] + 1 : 0;
  int v2 = (base + 2 < n) ? cnt[base + 2] + 1 : 0;
  int v3 = (base + 3 < n) ? cnt[base + 3] + 1 : 0;
  const int s = v0 + v1 + v2 + v3;
  sd[t] = s;
  __syncthreads();
  int acc = s;
#pragma unroll
  for (int o = 1; o < 256; o <<= 1) {
    int u = (t >= o) ? sd[t - o] : 0;
    __syncthreads();
    acc += u;
    sd[t] = acc;
    __syncthreads();
  }
  int excl = acc - s;
  if (base + 0 < n) rowp[base + 0] = excl;
  if (base + 1 < n) rowp[base + 1] = excl + v0;
  if (base + 2 < n) rowp[base + 2] = excl + v0 + v1;
  if (base + 3 < n) rowp[base + 3] = excl + v0 + v1 + v2;
  if (t == 255) bsum[blockIdx.x] = acc;
}

// pass 2: one wave scans <=64 block sums in-place to exclusive; bsum[nb]=total
__global__ void scan2_kernel(int* __restrict__ bsum, int nb) {
  const int lane = threadIdx.x;
  int v = (lane < nb) ? bsum[lane] : 0;
  int incl = v;
#pragma unroll
  for (int o = 1; o < 64; o <<= 1) {
    int u = __shfl_up(incl, o);
    if (lane >= o) incl += u;
  }
  if (lane < nb) bsum[lane] = incl - v;
  if (lane == 63) bsum[nb] = incl;
}

// pass 3: add block offsets; init cursor; write row_ptr[n]
__global__ void scan3_kernel(int* __restrict__ rowp, int* __restrict__ cursor,
                             const int* __restrict__ bsum, int n, int nb) {
  int i = blockIdx.x * 256 + threadIdx.x;
  if (i >= n) return;
  int v = rowp[i] + bsum[i >> 10];
  rowp[i] = v;
  cursor[i] = v;
  if (i == 0) rowp[n] = bsum[nb];
}

__global__ void scatter_kernel(const int* __restrict__ src,
                               const int* __restrict__ dst,
                               int* __restrict__ cursor,
                               int* __restrict__ col_src,
                               int* __restrict__ eid, int E_) {
  int e = blockIdx.x * 256 + threadIdx.x;
  if (e >= E_) return;
  int d = dst[e];
  int p = atomicAdd(&cursor[d], 1);
  col_src[p] = src[e];
  eid[p] = e;
}

// runs AFTER scatter completes -> self entry is last in each CSR row
__global__ void selfloop_kernel(int* __restrict__ cursor,
                                int* __restrict__ col_src,
                                int* __restrict__ eid, int n, int E_) {
  int i = blockIdx.x * 256 + threadIdx.x;
  if (i >= n) return;
  int p = atomicAdd(&cursor[i], 1);
  col_src[p] = i;
  eid[p] = E_ + i;
}

// --------------------------- comb (all layers) ------------------------------
// comb layout (48 floats): L0 h0 @0, L1 h0 @8 h1 @16, L2 h0 @24 h1 @32, L3 @40
__global__ void comb_all_kernel(const float* __restrict__ We0,
                                const float* __restrict__ ae0,
                                const float* __restrict__ We1,
                                const float* __restrict__ ae1,
                                const float* __restrict__ We2,
                                const float* __restrict__ ae2,
                                const float* __restrict__ We3,
                                const float* __restrict__ ae3,
                                float* __restrict__ comb) {
  int t = threadIdx.x;
  if (t >= 48) return;
  float s = 0.f;
  if (t < 8) {
    int d = t;
    for (int c = 0; c < 64; ++c) s += We0[d * 64 + c] * ae0[c];
  } else if (t < 24) {
    int idx = t - 8, h = idx >> 3, d = idx & 7;
    for (int c = 0; c < 64; ++c) s += We1[d * 128 + h * 64 + c] * ae1[h * 64 + c];
  } else if (t < 40) {
    int idx = t - 24, h = idx >> 3, d = idx & 7;
    for (int c = 0; c < 64; ++c) s += We2[d * 128 + h * 64 + c] * ae2[h * 64 + c];
  } else {
    int d = t - 40;
    for (int c = 0; c < 2; ++c) s += We3[d * 2 + c] * ae3[c];
  }
  comb[t] = s;
}

// --------------------------- edge prep -------------------------------------
// One wave per node: gather edge_attr for the row, accumulate sum (-> loop
// attr mean), and emit per-edge dots for all 4 layers. Self entry (last in
// row) gets dots of the mean attr.
__global__ __launch_bounds__(256) void edge_prep_kernel(
    const int* __restrict__ row_ptr, const int* __restrict__ eid,
    const float* __restrict__ ea, const float* __restrict__ comb,
    float* __restrict__ edot0, float* __restrict__ edot1,
    float* __restrict__ edot2, float* __restrict__ edot3, int n, int E_) {
  __shared__ float cb[48];
  if (threadIdx.x < 48) cb[threadIdx.x] = comb[threadIdx.x];
  __syncthreads();
  const int lane = threadIdx.x & 63;
  const int node = blockIdx.x * 4 + (threadIdx.x >> 6);
  if (node >= n) return;

  const int start = row_ptr[node];
  const int selfpos = row_ptr[node + 1] - 1;  // self entry is last

  float s0 = 0.f, s1 = 0.f, s2 = 0.f, s3 = 0.f, s4 = 0.f, s5 = 0.f, s6 = 0.f,
        s7 = 0.f;
  for (int i = start + lane; i < selfpos; i += 64) {
    int id = eid[i];
    const float4* v = reinterpret_cast<const float4*>(ea + (size_t)id * 8);
    float4 a = v[0], b = v[1];
    s0 += a.x; s1 += a.y; s2 += a.z; s3 += a.w;
    s4 += b.x; s5 += b.y; s6 += b.z; s7 += b.w;
    edot0[i] = dot8(a, b, cb + 0);
    edot1[2 * (size_t)i + 0] = dot8(a, b, cb + 8);
    edot1[2 * (size_t)i + 1] = dot8(a, b, cb + 16);
    edot2[2 * (size_t)i + 0] = dot8(a, b, cb + 24);
    edot2[2 * (size_t)i + 1] = dot8(a, b, cb + 32);
    edot3[i] = dot8(a, b, cb + 40);
  }
#pragma unroll
  for (int o = 32; o >= 1; o >>= 1) {
    s0 += __shfl_xor(s0, o); s1 += __shfl_xor(s1, o);
    s2 += __shfl_xor(s2, o); s3 += __shfl_xor(s3, o);
    s4 += __shfl_xor(s4, o); s5 += __shfl_xor(s5, o);
    s6 += __shfl_xor(s6, o); s7 += __shfl_xor(s7, o);
  }
  if (lane == 0) {
    float deg = (float)(selfpos - start);
    float inv = 1.f / fmaxf(deg, 1.f);
    float4 a = make_float4(s0 * inv, s1 * inv, s2 * inv, s3 * inv);
    float4 b = make_float4(s4 * inv, s5 * inv, s6 * inv, s7 * inv);
    int i = selfpos;
    edot0[i] = dot8(a, b, cb + 0);
    edot1[2 * (size_t)i + 0] = dot8(a, b, cb + 8);
    edot1[2 * (size_t)i + 1] = dot8(a, b, cb + 16);
    edot2[2 * (size_t)i + 0] = dot8(a, b, cb + 24);
    edot2[2 * (size_t)i + 1] = dot8(a, b, cb + 32);
    edot3[i] = dot8(a, b, cb + 40);
  }
}

// --------------------------- projection GEMM -------------------------------

// h = x @ W  (x: [n,64], W: [64,HC]); fused al_src/al_dst epilogue.
template <int HC, int H>
__global__ __launch_bounds__(256) void gemm_proj_kernel(
    const float* __restrict__ x, const float* __restrict__ W,
    const float* __restrict__ a_src, const float* __restrict__ a_dst,
    float* __restrict__ h, float* __restrict__ al_src,
    float* __restrict__ al_dst, int n) {
  constexpr int IN = 64;
  constexpr int C = HC / H;
  __shared__ float xs[32][IN];
  const int tid = threadIdx.x;
  const int j = tid % HC;
  const int rsub = tid / HC;
  constexpr int RPP = 256 / HC > 0 ? 256 / HC : 1;

  float wr[IN];
#pragma unroll
  for (int k = 0; k < IN; ++k) wr[k] = W[k * HC + j];
  const float asj = a_src[j];
  const float adj = a_dst[j];

  const int row0 = blockIdx.x * 32;
  {
    const float4* xv = reinterpret_cast<const float4*>(x);
    float4* xsv = reinterpret_cast<float4*>(&xs[0][0]);
    for (int i = tid; i < 32 * IN / 4; i += 256) {
      int r = i / (IN / 4);
      int row = row0 + r;
      float4 v = make_float4(0.f, 0.f, 0.f, 0.f);
      if (row < n) v = xv[(size_t)row * (IN / 4) + (i % (IN / 4))];
      xsv[i] = v;
    }
  }
  __syncthreads();

  for (int rb = 0; rb < 32; rb += RPP) {
    int r = rb + rsub;
    if (r >= 32) break;  // wave-uniform (only for HC=2 tails)
    int row = row0 + r;
    float acc = 0.f;
#pragma unroll
    for (int k4 = 0; k4 < IN / 4; ++k4) {
      float4 xv = *reinterpret_cast<const float4*>(&xs[r][k4 * 4]);
      acc += xv.x * wr[k4 * 4 + 0] + xv.y * wr[k4 * 4 + 1] +
             xv.z * wr[k4 * 4 + 2] + xv.w * wr[k4 * 4 + 3];
    }
    if (row < n) h[(size_t)row * HC + j] = acc;
    // fused al_src / al_dst reductions over the C lanes of each head
    float ps = acc * asj;
    float pd = acc * adj;
#pragma unroll
    for (int o = C / 2; o >= 1; o >>= 1) {
      ps += __shfl_xor(ps, o);
      pd += __shfl_xor(pd, o);
    }
    if (row < n && (j % C) == 0) {
      int hh = j / C;
      al_src[(size_t)row * H + hh] = ps;
      al_dst[(size_t)row * H + hh] = pd;
    }
  }
}

// --------------------------- fused node kernel ------------------------------
// softmax + aggregation; one wave per node; edot read contiguously.
template <int H, int C, bool CONCAT, bool RELU>
__global__ __launch_bounds__(256) void gat_node_kernel(
    const int* __restrict__ row_ptr, const int* __restrict__ col_src,
    const float* __restrict__ edot, const float* __restrict__ h_proj,
    const float* __restrict__ al_src, const float* __restrict__ al_dst,
    const float* __restrict__ bias, float* __restrict__ out, int n) {
  const int lane = threadIdx.x & 63;
  const int node = blockIdx.x * 4 + (threadIdx.x >> 6);
  if (node >= n) return;

  float adn[H];
#pragma unroll
  for (int h = 0; h < H; ++h) adn[h] = al_dst[(size_t)node * H + h];

  const int start = row_ptr[node];
  const int end = row_ptr[node + 1];

  float m[H], den[H], acc[H];
#pragma unroll
  for (int h = 0; h < H; ++h) { m[h] = -INFINITY; den[h] = 0.f; acc[h] = 0.f; }

  for (int base = start; base < end; base += 64) {
    const int i = base + lane;
    const bool valid = (i < end);
    int s = 0;
    float alpha[H];
    if (valid) {
      s = col_src[i];
      if (H == 1) {
        float a = al_src[s] + adn[0] + edot[i];
        alpha[0] = (a > 0.f) ? a : 0.2f * a;
      } else {
        float2 as2 = *reinterpret_cast<const float2*>(al_src + (size_t)s * 2);
        float2 ed = *reinterpret_cast<const float2*>(edot + (size_t)i * 2);
        float a0 = as2.x + adn[0] + ed.x;
        float a1 = as2.y + adn[1] + ed.y;
        alpha[0] = (a0 > 0.f) ? a0 : 0.2f * a0;
        if (H > 1) alpha[1] = (a1 > 0.f) ? a1 : 0.2f * a1;
      }
    } else {
#pragma unroll
      for (int h = 0; h < H; ++h) alpha[h] = -INFINITY;
    }

    float ex[H];
#pragma unroll
    for (int h = 0; h < H; ++h) {
      float cm = wave_max64(alpha[h]);
      float nm = fmaxf(m[h], cm);          // finite: every chunk has >=1 edge
      float r = expf(m[h] - nm);           // exp(-inf)=0 on first chunk
      ex[h] = valid ? expf(alpha[h] - nm) : 0.f;
      float cs = wave_sum64(ex[h]);
      den[h] = den[h] * r + cs;
      acc[h] *= r;
      m[h] = nm;
    }

    const int cntc = min(64, end - base);
    for (int t = 0; t < cntc; ++t) {
      int sv = __shfl(s, t);
      const float* hp = h_proj + (size_t)sv * (H * C);
#pragma unroll
      for (int h = 0; h < H; ++h) {
        float w = __shfl(ex[h], t);
        if (C >= 64 || lane < C) acc[h] += w * hp[h * C + lane];
      }
    }
  }

  if (lane < C) {
    if (CONCAT) {
#pragma unroll
      for (int h = 0; h < H; ++h) {
        float v = acc[h] / (den[h] + 1e-16f) + bias[h * C + lane];
        if (RELU) v = fmaxf(v, 0.f);
        out[(size_t)node * (H * C) + h * C + lane] = v;
      }
    } else {
      float v = 0.f;
#pragma unroll
      for (int h = 0; h < H; ++h) v += acc[h] / (den[h] + 1e-16f);
      v = v * (1.f / H) + bias[lane];
      if (RELU) v = fmaxf(v, 0.f);
      out[(size_t)node * C + lane] = v;
    }
  }
}

// --------------------------- launch ----------------------------------------

static inline size_t align_up(size_t v, size_t a) { return (v + a - 1) & ~(a - 1); }

extern "C" void kernel_launch(void* const* d_in, const int* in_sizes, int n_in,
                              void* d_out, int out_size, void* d_ws,
                              size_t ws_size, hipStream_t stream) {
  const float* x = (const float*)d_in[0];
  const int* ei = (const int*)d_in[1];
  const float* ea = (const float*)d_in[2];

  const int N = in_sizes[0] / 64;
  const int E = in_sizes[1] / 2;
  const int* src0 = ei;
  const int* dst0 = ei + E;
  const int M = E + N;  // CSR slots

  const float* W[4] = {(const float*)d_in[3], (const float*)d_in[9],
                       (const float*)d_in[15], (const float*)d_in[21]};
  const float* As[4] = {(const float*)d_in[4], (const float*)d_in[10],
                        (const float*)d_in[16], (const float*)d_in[22]};
  const float* Ad[4] = {(const float*)d_in[5], (const float*)d_in[11],
                        (const float*)d_in[17], (const float*)d_in[23]};
  const float* We[4] = {(const float*)d_in[6], (const float*)d_in[12],
                        (const float*)d_in[18], (const float*)d_in[24]};
  const float* Ae[4] = {(const float*)d_in[7], (const float*)d_in[13],
                        (const float*)d_in[19], (const float*)d_in[25]};
  const float* B[4] = {(const float*)d_in[8], (const float*)d_in[14],
                       (const float*)d_in[20], (const float*)d_in[26]};

  // workspace carve-up
  char* p = (char*)d_ws;
  size_t off = 0;
  auto carve = [&](size_t bytes) {
    void* r = p + off;
    off = align_up(off + bytes, 256);
    return r;
  };
  int* cnt = (int*)carve((size_t)N * 4);
  int* row_ptr = (int*)carve((size_t)(N + 1) * 4);
  int* cursor = (int*)carve((size_t)N * 4);
  int* bsum = (int*)carve((size_t)256 * 4);
  int* col_src = (int*)carve((size_t)M * 4);
  int* eid = (int*)carve((size_t)M * 4);
  float* comb = (float*)carve(256);
  float* edot0 = (float*)carve((size_t)M * 4);
  float* edot1 = (float*)carve((size_t)M * 8);
  float* edot2 = (float*)carve((size_t)M * 8);
  float* edot3 = (float*)carve((size_t)M * 4);
  float* al_src = (float*)carve((size_t)N * 2 * 4);
  float* al_dst = (float*)carve((size_t)N * 2 * 4);
  float* h_proj = (float*)carve((size_t)N * 128 * 4);
  float* buf_a = (float*)carve((size_t)N * 64 * 4);
  float* buf_b = (float*)carve((size_t)N * 64 * 4);
  (void)ws_size;

  const int nb = (N + 1023) / 1024;  // <=64 required (N<=65536)

  // ---- CSR + per-edge dots (graph is layer-invariant) ----
  hipMemsetAsync(cnt, 0, (size_t)N * 4, stream);
  hist_kernel<<<(E + 255) / 256, 256, 0, stream>>>(dst0, cnt, E);
  scan1_kernel<<<nb, 256, 0, stream>>>(cnt, row_ptr, bsum, N);
  scan2_kernel<<<1, 64, 0, stream>>>(bsum, nb);
  scan3_kernel<<<(N + 255) / 256, 256, 0, stream>>>(row_ptr, cursor, bsum, N, nb);
  scatter_kernel<<<(E + 255) / 256, 256, 0, stream>>>(src0, dst0, cursor,
                                                      col_src, eid, E);
  selfloop_kernel<<<(N + 255) / 256, 256, 0, stream>>>(cursor, col_src, eid, N, E);
  comb_all_kernel<<<1, 64, 0, stream>>>(We[0], Ae[0], We[1], Ae[1], We[2],
                                        Ae[2], We[3], Ae[3], comb);
  edge_prep_kernel<<<(N + 3) / 4, 256, 0, stream>>>(
      row_ptr, eid, ea, comb, edot0, edot1, edot2, edot3, N, E);

  const int gemm_grid = (N + 31) / 32;
  const int node_grid = (N + 3) / 4;

  // ---- layer 0: in64 -> H1,C64, concat, relu ----
  gemm_proj_kernel<64, 1><<<gemm_grid, 256, 0, stream>>>(
      x, W[0], As[0], Ad[0], h_proj, al_src, al_dst, N);
  gat_node_kernel<1, 64, true, true><<<node_grid, 256, 0, stream>>>(
      row_ptr, col_src, edot0, h_proj, al_src, al_dst, B[0], buf_a, N);

  // ---- layer 1: 64 -> H2,C64, mean, relu ----
  gemm_proj_kernel<128, 2><<<gemm_grid, 256, 0, stream>>>(
      buf_a, W[1], As[1], Ad[1], h_proj, al_src, al_dst, N);
  gat_node_kernel<2, 64, false, true><<<node_grid, 256, 0, stream>>>(
      row_ptr, col_src, edot1, h_proj, al_src, al_dst, B[1], buf_b, N);

  // ---- layer 2: 64 -> H2,C64, mean, relu ----
  gemm_proj_kernel<128, 2><<<gemm_grid, 256, 0, stream>>>(
      buf_b, W[2], As[2], Ad[2], h_proj, al_src, al_dst, N);
  gat_node_kernel<2, 64, false, true><<<node_grid, 256, 0, stream>>>(
      row_ptr, col_src, edot2, h_proj, al_src, al_dst, B[2], buf_a, N);

  // ---- layer 3: 64 -> H1,C2, concat, no relu ----
  gemm_proj_kernel<2, 1><<<gemm_grid, 256, 0, stream>>>(
      buf_a, W[3], As[3], Ad[3], h_proj, al_src, al_dst, N);
  gat_node_kernel<1, 2, true, false><<<node_grid, 256, 0, stream>>>(
      row_ptr, col_src, edot3, h_proj, al_src, al_dst, B[3], (float*)d_out, N);
}